// Round 15
// baseline (86.604 us; speedup 1.0000x reference)
//
#include <hip/hip_runtime.h>
#include <math.h>

#define NB 36
#define W 640
#define H 640
#define NSAMP 64
#define RPB 40                     // rows per block
#define BPS 16                     // blocks per sample (16*40 = 640)
#define NBLK (NSAMP * BPS)         // 1024 (co-resident: 4 blocks/CU)
#define FIX_SCALE 4194304.0f       // 2^22: row prefix < 640*2^22 < 2^32
#define INV_FIX (1.0f/4194304.0f)
#define CNT_SHIFT 44               // sample-bin sum < 2^40.7 < 2^44
#define SUM_MASK ((1ull << CNT_SHIFT) - 1)
#define AMB 1e-6

typedef float __attribute__((ext_vector_type(4))) f32x4;

__device__ __forceinline__ f32x4 ldnt(const float* p) {
    return __builtin_nontemporal_load((const f32x4*)(p));
}

// cot((m-18)*pi/18) — compile-time; deviations vs libm (~1e-13 px) only
// matter inside the AMB razor band where bin_slow decides. Valid R9-R14.
__device__ __constant__ double COT[36] = {
    0.0,
    5.6712818196177095,  2.7474774194546223,  1.7320508075688773,
    1.1917535925942100,  0.8390996311772800,  0.5773502691896258,
    0.3639702342662024,  0.1763269807084650,  0.0,
    -0.1763269807084650, -0.3639702342662024, -0.5773502691896258,
    -0.8390996311772800, -1.1917535925942100, -1.7320508075688773,
    -2.7474774194546223, -5.6712818196177095,
    0.0,
    5.6712818196177095,  2.7474774194546223,  1.7320508075688773,
    1.1917535925942100,  0.8390996311772800,  0.5773502691896258,
    0.3639702342662024,  0.1763269807084650,  0.0,
    -0.1763269807084650, -0.3639702342662024, -0.5773502691896258,
    -0.8390996311772800, -1.1917535925942100, -1.7320508075688773,
    -2.7474774194546223, -5.6712818196177095
};

// Exact f64 golden chain (validated: absmax==0 in rounds 3-14).
__device__ __forceinline__ int bin_slow(int x, int y, double cxd, double cyd) {
    const double PI_D    = 3.141592653589793;
    const double TWOPI_D = 6.283185307179586;
    double t  = (atan2((double)y - cyd, (double)x - cxd) + PI_D) / TWOPI_D;
    double bd = t * 36.0;
    int k = (int)bd;
    k = k < 0 ? 0 : k;
    return k > NB - 1 ? NB - 1 : k;
}

// one DPP scan step: x += shifted(x)  (validated rounds 7-14)
#define SCAN_STEP(x, ctrl, rmask)                                             \
    x += (unsigned)__builtin_amdgcn_update_dpp(0, (int)(x), (ctrl), (rmask),  \
                                               0xf, false)

__global__ __launch_bounds__(256) void acl_fused(const float* __restrict__ mask,
                                                 const float* __restrict__ bbox,
                                                 unsigned long long* __restrict__ ws) {
    __shared__ int A_l[RPB][18];               // ascending segment right-ends
    __shared__ int sgn_l[RPB];                 // sign(dy) per row
    __shared__ __align__(16) unsigned srow[8][768];  // 2 slabs per wave
    __shared__ unsigned long long lbin[NB];
    __shared__ int slast;

    const int tid = threadIdx.x;
    const int b   = blockIdx.x >> 4;           // sample
    const int rg  = blockIdx.x & (BPS - 1);    // 40-row group
    const int y0  = rg * RPB;

    if (tid < NB) lbin[tid] = 0ull;
    if (tid < RPB) A_l[tid][17] = W - 1;       // sentinel

    // ---- prologue: issue pairs 0 and 1 (12 nt loads) before phase-1 ------
    const int wid = tid >> 6, lane = tid & 63;
    const float* wb = mask + (size_t)b * (W * H) + (size_t)(y0 + wid * 10) * W;
    const f32x4 z4 = 0.0f;
    const int o0 = lane * 4, o1 = lane * 4 + 256, o2 = lane * 4 + 512;

    f32x4 cA0 = ldnt(wb + o0),     cA1 = ldnt(wb + o1);
    f32x4 cA2 = (lane < 32) ? ldnt(wb + o2) : z4;
    f32x4 cB0 = ldnt(wb + W + o0), cB1 = ldnt(wb + W + o1);
    f32x4 cB2 = (lane < 32) ? ldnt(wb + W + o2) : z4;
    f32x4 dA0 = ldnt(wb + 2*W + o0), dA1 = ldnt(wb + 2*W + o1);
    f32x4 dA2 = (lane < 32) ? ldnt(wb + 2*W + o2) : z4;
    f32x4 dB0 = ldnt(wb + 3*W + o0), dB1 = ldnt(wb + 3*W + o1);
    f32x4 dB2 = (lane < 32) ? ldnt(wb + 3*W + o2) : z4;

    const double cxd = (double)bbox[b * 4 + 0] * 640.0;   // exact in f64
    const double cyd = (double)bbox[b * 4 + 1] * 640.0;

    // ---- phase 1: 40 rows x 17 cutpoints (validated razor logic) ---------
    for (int task = tid; task < RPB * 17; task += 256) {
        const int rl = task / 17, mi = task % 17;
        const int y  = y0 + rl;
        const double dy = (double)y - cyd;
        int i, a;
        if (dy == 0.0) {
            if (mi == 0) sgn_l[rl] = 0;
            i = mi;
            a = (mi == 0) ? ((int)ceil(cxd) - 1) : (W - 1);
        } else {
            const bool dp = (dy > 0.0);
            if (mi == 0) sgn_l[rl] = dp ? 1 : -1;
            const int m = dp ? (19 + mi) : (1 + mi);
            double x = cxd + dy * COT[m];
            x = fmin(fmax(x, -2.0), 642.0);
            double g  = x + 2.0;
            int    gi = (int)g;
            double fr = g - (double)gi;
            int v = dp ? (gi - 2)    // floor(x): max px with bin >= m
                       : (gi - 1);   // ceil(x):  min px with bin >= m
            if (fr < AMB || fr > 1.0 - AMB) {
                int xa = (int)(x + 2.5) - 2;
                if (xa >= 0 && xa <= W - 1) {
                    int kb = bin_slow(xa, y, cxd, cyd);
                    if (dp) v = (kb >= m) ? xa : xa - 1;
                    else    v = (kb >= m) ? xa : xa + 1;
                }
            }
            if (dp) { i = 16 - mi; a = v; }      // ascending index
            else    { i = mi;      a = v - 1; }
        }
        a = a < -1 ? -1 : (a > W - 1 ? W - 1 : a);
        A_l[rl][i] = a;
    }
    __syncthreads();

    // ---- phase 2: 5 row-pairs per wave, depth-2-pair ring (R13-proven) ---
    unsigned long long accPs = 0ull, accNs = 0ull;
    unsigned accPc = 0u, accNc = 0u;

    #pragma unroll
    for (int j = 0; j < 5; j++) {
        const int rl0 = wid * 10 + 2 * j;
        f32x4 nA0 = z4, nA1 = z4, nA2 = z4, nB0 = z4, nB1 = z4, nB2 = z4;
        if (j < 3) {                           // prefetch pair j+2
            const float* pa = wb + (size_t)(2 * j + 4) * W;
            const float* pb = wb + (size_t)(2 * j + 5) * W;
            nA0 = ldnt(pa + o0); nA1 = ldnt(pa + o1);
            nA2 = (lane < 32) ? ldnt(pa + o2) : z4;
            nB0 = ldnt(pb + o0); nB1 = ldnt(pb + o1);
            nB2 = (lane < 32) ? ldnt(pb + o2) : z4;
        }

        unsigned carryA = 0u, carryB = 0u;
        #pragma unroll
        for (int s = 0; s < 3; s++) {
            const f32x4 va = (s == 0) ? cA0 : (s == 1) ? cA1 : cA2;
            const f32x4 vb = (s == 0) ? cB0 : (s == 1) ? cB1 : cB2;
            const unsigned qa0 = __float2uint_rn(va.x * FIX_SCALE);
            const unsigned qa1 = __float2uint_rn(va.y * FIX_SCALE);
            const unsigned qa2 = __float2uint_rn(va.z * FIX_SCALE);
            const unsigned qa3 = __float2uint_rn(va.w * FIX_SCALE);
            const unsigned qb0 = __float2uint_rn(vb.x * FIX_SCALE);
            const unsigned qb1 = __float2uint_rn(vb.y * FIX_SCALE);
            const unsigned qb2 = __float2uint_rn(vb.z * FIX_SCALE);
            const unsigned qb3 = __float2uint_rn(vb.w * FIX_SCALE);
            const unsigned pa0 = qa0, pa1 = pa0 + qa1, pa2 = pa1 + qa2, pa3 = pa2 + qa3;
            const unsigned pb0 = qb0, pb1 = pb0 + qb1, pb2 = pb1 + qb2, pb3 = pb2 + qb3;

            unsigned xa = pa3, xb = pb3;       // interleaved 64-lane scans
            SCAN_STEP(xa, 0x111, 0xf); SCAN_STEP(xb, 0x111, 0xf);
            SCAN_STEP(xa, 0x112, 0xf); SCAN_STEP(xb, 0x112, 0xf);
            SCAN_STEP(xa, 0x114, 0xf); SCAN_STEP(xb, 0x114, 0xf);
            SCAN_STEP(xa, 0x118, 0xf); SCAN_STEP(xb, 0x118, 0xf);
            SCAN_STEP(xa, 0x142, 0xa); SCAN_STEP(xb, 0x142, 0xa);
            SCAN_STEP(xa, 0x143, 0xc); SCAN_STEP(xb, 0x143, 0xc);

            const unsigned baA = carryA + (xa - pa3);
            const unsigned baB = carryB + (xb - pb3);
            uint4 wa, wbv;
            wa.x  = baA + pa0; wa.y  = baA + pa1; wa.z  = baA + pa2; wa.w  = baA + pa3;
            wbv.x = baB + pb0; wbv.y = baB + pb1; wbv.z = baB + pb2; wbv.w = baB + pb3;
            *((uint4*)&srow[wid][s * 256 + lane * 4])     = wa;
            *((uint4*)&srow[wid + 4][s * 256 + lane * 4]) = wbv;
            carryA += (unsigned)__builtin_amdgcn_readlane((int)xa, 63);
            carryB += (unsigned)__builtin_amdgcn_readlane((int)xb, 63);
        }

        // extract both rows; sL/aL via wave_shr:1 DPP (one ds_read per row)
        #pragma unroll
        for (int r = 0; r < 2; r++) {
            const int rl = rl0 + r;
            const int slab = wid + 4 * r;
            const int aR = A_l[rl][(lane < 18) ? lane : 17];
            const int idx = aR & ~(aR >> 31);              // max(aR, 0)
            const unsigned sRraw = srow[slab][idx];
            const unsigned sR = (aR >= 0) ? sRraw : 0u;
            const int aL =
                __builtin_amdgcn_update_dpp(-1, aR, 0x138, 0xf, 0xf, false);
            const unsigned sL = (unsigned)
                __builtin_amdgcn_update_dpp(0, (int)sR, 0x138, 0xf, 0xf, false);
            if (lane < 18) {
                const int cnt = aR - aL;
                if (cnt > 0) {
                    const unsigned seg = sR - sL;
                    const int sg = sgn_l[rl];
                    if (sg > 0)      { accPc += (unsigned)cnt; accPs += seg; }
                    else if (sg < 0) { accNc += (unsigned)cnt; accNs += seg; }
                    else atomicAdd(&lbin[(lane == 0) ? 35 : 18],
                                   ((unsigned long long)cnt << CNT_SHIFT)
                                   + (unsigned long long)seg);
                }
            }
        }
        cA0 = dA0; cA1 = dA1; cA2 = dA2; cB0 = dB0; cB1 = dB1; cB2 = dB2;
        dA0 = nA0; dA1 = nA1; dA2 = nA2; dB0 = nB0; dB1 = nB1; dB2 = nB2;
    }

    // ---- flush: regs -> lbin -> transposed partial slab (agent stores) ---
    if (lane < 18) {
        if (accPc) atomicAdd(&lbin[35 - lane],
                             ((unsigned long long)accPc << CNT_SHIFT) + accPs);
        if (accNc) atomicAdd(&lbin[lane],
                             ((unsigned long long)accNc << CNT_SHIFT) + accNs);
    }
    __syncthreads();
    if (tid < NB)
        __hip_atomic_store(&ws[(size_t)tid * NBLK + blockIdx.x], lbin[tid],
                           __ATOMIC_RELAXED, __HIP_MEMORY_SCOPE_AGENT);

    // ---- last-block finalize (rocPRIM pattern) ----------------------------
    unsigned* cnt_p = (unsigned*)(ws + (size_t)NB * NBLK);
    __syncthreads();
    if (tid == 0) {
        __threadfence();
        unsigned old = atomicAdd(cnt_p, 1u);
        slast = (old == NBLK - 1);
    }
    __syncthreads();
    if (!slast) return;
    __threadfence();

    __shared__ unsigned nund[256];
    const int fb = tid & 63, fq = tid >> 6;    // sample, bin-quarter
    unsigned cu = 0;
    #pragma unroll
    for (int kk = 0; kk < 9; kk++) {
        const int k = fq * 9 + kk;
        const unsigned long long* base = ws + (size_t)k * NBLK + (size_t)fb * BPS;
        unsigned long long tot = 0ull;
        #pragma unroll
        for (int g = 0; g < BPS; g++)
            tot += __hip_atomic_load(&base[g], __ATOMIC_RELAXED,
                                     __HIP_MEMORY_SCOPE_AGENT);
        const unsigned long long c = tot >> CNT_SHIFT;
        const float sum = (float)(tot & SUM_MASK) * INV_FIX;
        const float act = (c != 0ull) ? (sum / (float)c) : 0.0f;
        if (act < 0.1f) cu++;
    }
    nund[tid] = cu;
    __syncthreads();
    if (tid == 0) {
        float acc = 0.0f;
        for (int i = 0; i < NSAMP; i++) {
            const unsigned n = nund[i] + nund[64 + i] + nund[128 + i] + nund[192 + i];
            acc += (float)n / 36.0f;           // same float chain as rounds 3-14
        }
        float* out = (float*)(ws + (size_t)NB * NBLK + 1);
        ((volatile float*)out)[0] = 0.0f;      // keep slot layout simple
        // final result written via out pointer passed in ws+2 slot below
    }
    // write output (pointer passed via constant arg is cleaner: see launch)
    if (tid == 0) {
        float acc = 0.0f;
        for (int i = 0; i < NSAMP; i++) {
            const unsigned n = nund[i] + nund[64 + i] + nund[128 + i] + nund[192 + i];
            acc += (float)n / 36.0f;
        }
        float** outpp = (float**)(ws + (size_t)NB * NBLK + 2);
        float* outp = *outpp;
        outp[0] = acc / 64.0f;                 // PENALTY_WEIGHT == 1
    }
}

// store d_out pointer into ws so the fused kernel can find it (written
// host-side before capture? no host writes allowed -> use a tiny kernel)
__global__ void acl_setptr(unsigned long long* __restrict__ ws, float* out) {
    if (threadIdx.x == 0 && blockIdx.x == 0) {
        float** outpp = (float**)(ws + (size_t)NB * NBLK + 2);
        *outpp = out;
    }
}

extern "C" void kernel_launch(void* const* d_in, const int* in_sizes, int n_in,
                              void* d_out, int out_size, void* d_ws, size_t ws_size,
                              hipStream_t stream) {
    const float* mask = (const float*)d_in[0];
    const float* bbox = (const float*)d_in[1];
    unsigned long long* ws = (unsigned long long*)d_ws;

    // reset the last-block counter (8 B) each call; graph-capturable memset
    hipMemsetAsync((void*)(ws + (size_t)NB * NBLK), 0, 8, stream);
    acl_setptr<<<dim3(1), dim3(64), 0, stream>>>(ws, (float*)d_out);
    acl_fused<<<dim3(NBLK), dim3(256), 0, stream>>>(mask, bbox, ws);
}

// Round 16
// 34.024 us; speedup vs baseline: 2.5454x; 2.5454x over previous
//
#include <hip/hip_runtime.h>
#include <math.h>

#define NB 36
#define W 640
#define H 640
#define NSAMP 64
#define RPB 40                     // rows per block
#define BPS 16                     // blocks per sample (16*40 = 640)
#define NBLK (NSAMP * BPS)         // 1024
#define FIX_SCALE 4194304.0f       // 2^22: row prefix < 640*2^22 < 2^32
#define INV_FIX (1.0f/4194304.0f)
#define CNT_SHIFT 44               // sample-bin sum < 2^40.7 < 2^44
#define SUM_MASK ((1ull << CNT_SHIFT) - 1)
#define AMB 1e-6

typedef float __attribute__((ext_vector_type(4))) f32x4;

__device__ __forceinline__ f32x4 ldnt(const float* p) {
    return __builtin_nontemporal_load((const f32x4*)p);
}

// cot((m-18)*pi/18) — compile-time, <1e-16 rel err; deviations from libm
// (~1e-13 px on cutpoints) only matter inside the AMB razor band, where
// bin_slow (exact golden) decides. Validated R9-R15 (absmax=0).
__device__ __constant__ double COT[36] = {
    0.0,
    5.6712818196177095,  2.7474774194546223,  1.7320508075688773,
    1.1917535925942100,  0.8390996311772800,  0.5773502691896258,
    0.3639702342662024,  0.1763269807084650,  0.0,
    -0.1763269807084650, -0.3639702342662024, -0.5773502691896258,
    -0.8390996311772800, -1.1917535925942100, -1.7320508075688773,
    -2.7474774194546223, -5.6712818196177095,
    0.0,
    5.6712818196177095,  2.7474774194546223,  1.7320508075688773,
    1.1917535925942100,  0.8390996311772800,  0.5773502691896258,
    0.3639702342662024,  0.1763269807084650,  0.0,
    -0.1763269807084650, -0.3639702342662024, -0.5773502691896258,
    -0.8390996311772800, -1.1917535925942100, -1.7320508075688773,
    -2.7474774194546223, -5.6712818196177095
};

// Exact f64 golden chain (validated: absmax==0 in rounds 3-15).
__device__ __forceinline__ int bin_slow(int x, int y, double cxd, double cyd) {
    const double PI_D    = 3.141592653589793;
    const double TWOPI_D = 6.283185307179586;
    double t  = (atan2((double)y - cyd, (double)x - cxd) + PI_D) / TWOPI_D;
    double bd = t * 36.0;
    int k = (int)bd;
    k = k < 0 ? 0 : k;
    return k > NB - 1 ? NB - 1 : k;
}

// one DPP scan step: x += shifted(x)  (validated rounds 7-15)
#define SCAN_STEP(x, ctrl, rmask)                                             \
    x += (unsigned)__builtin_amdgcn_update_dpp(0, (int)(x), (ctrl), (rmask),  \
                                               0xf, false)

__global__ __launch_bounds__(256) void acl_main(const float* __restrict__ mask,
                                                const float* __restrict__ bbox,
                                                unsigned long long* __restrict__ ws) {
    __shared__ int A_l[RPB][18];               // ascending segment right-ends
    __shared__ int sgn_l[RPB];                 // sign(dy) per row
    __shared__ __align__(16) unsigned srow[8][768];  // 2 slabs per wave
    __shared__ unsigned long long lbin[NB];

    const int tid = threadIdx.x;
    const int b   = blockIdx.x >> 4;           // sample
    const int rg  = blockIdx.x & (BPS - 1);    // 40-row group
    const int y0  = rg * RPB;

    if (tid < NB) lbin[tid] = 0ull;
    if (tid < RPB) A_l[tid][17] = W - 1;       // sentinel

    // ---- prologue: issue pairs 0 and 1 (12 nt loads) before phase-1 ------
    const int wid = tid >> 6, lane = tid & 63;
    const float* wb = mask + (size_t)b * (W * H) + (size_t)(y0 + wid * 10) * W;
    const f32x4 z4 = 0.0f;
    const int o0 = lane * 4, o1 = lane * 4 + 256, o2 = lane * 4 + 512;

    f32x4 cA0 = ldnt(wb + o0),     cA1 = ldnt(wb + o1);
    f32x4 cA2 = (lane < 32) ? ldnt(wb + o2) : z4;
    f32x4 cB0 = ldnt(wb + W + o0), cB1 = ldnt(wb + W + o1);
    f32x4 cB2 = (lane < 32) ? ldnt(wb + W + o2) : z4;
    f32x4 dA0 = ldnt(wb + 2*W + o0), dA1 = ldnt(wb + 2*W + o1);
    f32x4 dA2 = (lane < 32) ? ldnt(wb + 2*W + o2) : z4;
    f32x4 dB0 = ldnt(wb + 3*W + o0), dB1 = ldnt(wb + 3*W + o1);
    f32x4 dB2 = (lane < 32) ? ldnt(wb + 3*W + o2) : z4;

    const double cxd = (double)bbox[b * 4 + 0] * 640.0;   // exact in f64
    const double cyd = (double)bbox[b * 4 + 1] * 640.0;

    // ---- phase 1: 40 rows x 17 cutpoints (validated razor logic) ---------
    for (int task = tid; task < RPB * 17; task += 256) {
        const int rl = task / 17, mi = task % 17;
        const int y  = y0 + rl;
        const double dy = (double)y - cyd;
        int i, a;
        if (dy == 0.0) {
            if (mi == 0) sgn_l[rl] = 0;
            i = mi;
            a = (mi == 0) ? ((int)ceil(cxd) - 1) : (W - 1);
        } else {
            const bool dp = (dy > 0.0);
            if (mi == 0) sgn_l[rl] = dp ? 1 : -1;
            const int m = dp ? (19 + mi) : (1 + mi);
            double x = cxd + dy * COT[m];
            x = fmin(fmax(x, -2.0), 642.0);
            double g  = x + 2.0;
            int    gi = (int)g;
            double fr = g - (double)gi;
            int v = dp ? (gi - 2)    // floor(x): max px with bin >= m
                       : (gi - 1);   // ceil(x):  min px with bin >= m
            if (fr < AMB || fr > 1.0 - AMB) {
                int xa = (int)(x + 2.5) - 2;
                if (xa >= 0 && xa <= W - 1) {
                    int kb = bin_slow(xa, y, cxd, cyd);
                    if (dp) v = (kb >= m) ? xa : xa - 1;
                    else    v = (kb >= m) ? xa : xa + 1;
                }
            }
            if (dp) { i = 16 - mi; a = v; }      // ascending index
            else    { i = mi;      a = v - 1; }
        }
        a = a < -1 ? -1 : (a > W - 1 ? W - 1 : a);
        A_l[rl][i] = a;
    }
    __syncthreads();

    // ---- phase 2: 5 row-pairs per wave, depth-2-pair register ring -------
    unsigned long long accPs = 0ull, accNs = 0ull;
    unsigned accPc = 0u, accNc = 0u;

    #pragma unroll
    for (int j = 0; j < 5; j++) {
        const int rl0 = wid * 10 + 2 * j;      // block-local row of pair[0]
        f32x4 nA0 = z4, nA1 = z4, nA2 = z4, nB0 = z4, nB1 = z4, nB2 = z4;
        if (j < 3) {                           // prefetch pair j+2
            const float* pa = wb + (size_t)(2 * j + 4) * W;
            const float* pb = wb + (size_t)(2 * j + 5) * W;
            nA0 = ldnt(pa + o0); nA1 = ldnt(pa + o1);
            nA2 = (lane < 32) ? ldnt(pa + o2) : z4;
            nB0 = ldnt(pb + o0); nB1 = ldnt(pb + o1);
            nB2 = (lane < 32) ? ldnt(pb + o2) : z4;
        }

        // two independent scans (rows rl0, rl0+1) -> slabs wid, wid+4
        unsigned carryA = 0u, carryB = 0u;
        #pragma unroll
        for (int s = 0; s < 3; s++) {
            const f32x4 va = (s == 0) ? cA0 : (s == 1) ? cA1 : cA2;
            const f32x4 vb = (s == 0) ? cB0 : (s == 1) ? cB1 : cB2;
            const unsigned qa0 = __float2uint_rn(va.x * FIX_SCALE);
            const unsigned qa1 = __float2uint_rn(va.y * FIX_SCALE);
            const unsigned qa2 = __float2uint_rn(va.z * FIX_SCALE);
            const unsigned qa3 = __float2uint_rn(va.w * FIX_SCALE);
            const unsigned qb0 = __float2uint_rn(vb.x * FIX_SCALE);
            const unsigned qb1 = __float2uint_rn(vb.y * FIX_SCALE);
            const unsigned qb2 = __float2uint_rn(vb.z * FIX_SCALE);
            const unsigned qb3 = __float2uint_rn(vb.w * FIX_SCALE);
            const unsigned pa0 = qa0, pa1 = pa0 + qa1, pa2 = pa1 + qa2, pa3 = pa2 + qa3;
            const unsigned pb0 = qb0, pb1 = pb0 + qb1, pb2 = pb1 + qb2, pb3 = pb2 + qb3;

            unsigned xa = pa3, xb = pb3;       // interleaved 64-lane scans
            SCAN_STEP(xa, 0x111, 0xf); SCAN_STEP(xb, 0x111, 0xf);
            SCAN_STEP(xa, 0x112, 0xf); SCAN_STEP(xb, 0x112, 0xf);
            SCAN_STEP(xa, 0x114, 0xf); SCAN_STEP(xb, 0x114, 0xf);
            SCAN_STEP(xa, 0x118, 0xf); SCAN_STEP(xb, 0x118, 0xf);
            SCAN_STEP(xa, 0x142, 0xa); SCAN_STEP(xb, 0x142, 0xa);
            SCAN_STEP(xa, 0x143, 0xc); SCAN_STEP(xb, 0x143, 0xc);

            const unsigned baA = carryA + (xa - pa3);
            const unsigned baB = carryB + (xb - pb3);
            uint4 wa, wbv;
            wa.x  = baA + pa0; wa.y  = baA + pa1; wa.z  = baA + pa2; wa.w  = baA + pa3;
            wbv.x = baB + pb0; wbv.y = baB + pb1; wbv.z = baB + pb2; wbv.w = baB + pb3;
            *((uint4*)&srow[wid][s * 256 + lane * 4])     = wa;
            *((uint4*)&srow[wid + 4][s * 256 + lane * 4]) = wbv;
            carryA += (unsigned)__builtin_amdgcn_readlane((int)xa, 63);
            carryB += (unsigned)__builtin_amdgcn_readlane((int)xb, 63);
        }

        if (lane < 18) {                       // extract both rows (one drain)
            #pragma unroll
            for (int r = 0; r < 2; r++) {
                const int rl = rl0 + r;
                const int slab = wid + 4 * r;
                const int aR = A_l[rl][lane];
                const int aL = (lane == 0) ? -1 : A_l[rl][lane - 1];
                const int cnt = aR - aL;
                if (cnt > 0) {                 // cnt>0 => aR >= 0
                    const unsigned sR = srow[slab][aR];
                    const unsigned sL = (aL >= 0) ? srow[slab][aL] : 0u;
                    const unsigned seg = sR - sL;
                    const int sg = sgn_l[rl];
                    if (sg > 0)      { accPc += (unsigned)cnt; accPs += seg; }
                    else if (sg < 0) { accNc += (unsigned)cnt; accNs += seg; }
                    else atomicAdd(&lbin[(lane == 0) ? 35 : 18],
                                   ((unsigned long long)cnt << CNT_SHIFT)
                                   + (unsigned long long)seg);
                }
            }
        }
        // rotate ring: current <- next, next <- prefetched
        cA0 = dA0; cA1 = dA1; cA2 = dA2; cB0 = dB0; cB1 = dB1; cB2 = dB2;
        dA0 = nA0; dA1 = nA1; dA2 = nA2; dB0 = nB0; dB1 = nB1; dB2 = nB2;
    }

    // ---- flush: regs -> lbin -> transposed partial slab (plain stores) ---
    if (lane < 18) {
        if (accPc) atomicAdd(&lbin[35 - lane],
                             ((unsigned long long)accPc << CNT_SHIFT) + accPs);
        if (accNc) atomicAdd(&lbin[lane],
                             ((unsigned long long)accNc << CNT_SHIFT) + accNs);
    }
    __syncthreads();
    if (tid < NB)
        ws[(size_t)tid * NBLK + blockIdx.x] = lbin[tid];
}

__global__ __launch_bounds__(256) void acl_final(const unsigned long long* __restrict__ ws,
                                                 float* __restrict__ out) {
    __shared__ unsigned nund[256];
    __shared__ float s[NSAMP];
    const int tid = threadIdx.x;
    const int b = tid & 63, q = tid >> 6;      // sample, bin-quarter
    unsigned cu = 0;
    #pragma unroll
    for (int kk = 0; kk < 9; kk++) {
        const int k = q * 9 + kk;
        const unsigned long long* base = ws + (size_t)k * NBLK + (size_t)b * BPS;
        unsigned long long t0 = 0ull, t1 = 0ull;
        #pragma unroll
        for (int g = 0; g < BPS; g += 2) {     // 128B contiguous, coalesced
            t0 += base[g];
            t1 += base[g + 1];
        }
        const unsigned long long tot = t0 + t1;
        const unsigned long long cnt = tot >> CNT_SHIFT;
        const float sum = (float)(tot & SUM_MASK) * INV_FIX;
        const float act = (cnt != 0ull) ? (sum / (float)cnt) : 0.0f;
        if (act < 0.1f) cu++;
    }
    nund[tid] = cu;
    __syncthreads();
    if (tid < NSAMP) {
        const unsigned n = nund[tid] + nund[64 + tid] + nund[128 + tid] + nund[192 + tid];
        s[tid] = (float)n / 36.0f;             // same float chain as rounds 3-15
    }
    __syncthreads();
    if (tid == 0) {
        float acc = 0.0f;
        for (int i = 0; i < NSAMP; i++) acc += s[i];
        out[0] = acc / 64.0f;                  // PENALTY_WEIGHT == 1
    }
}

extern "C" void kernel_launch(void* const* d_in, const int* in_sizes, int n_in,
                              void* d_out, int out_size, void* d_ws, size_t ws_size,
                              hipStream_t stream) {
    const float* mask = (const float*)d_in[0];
    const float* bbox = (const float*)d_in[1];
    unsigned long long* ws = (unsigned long long*)d_ws;

    acl_main<<<dim3(NBLK), dim3(256), 0, stream>>>(mask, bbox, ws);
    acl_final<<<dim3(1), dim3(256), 0, stream>>>(ws, (float*)d_out);
}